// Round 18
// baseline (1086.088 us; speedup 1.0000x reference)
//
#include <hip/hip_runtime.h>
#include <hip/hip_bf16.h>
#include <stdint.h>

#define DIM_H 2048
#define DIM_I 8192
#define TOKENS 8192
#define RB256 34            // max 256-row compacted blocks (32 + 2 pad)
#define CROWS (RB256*256)   // 8704

typedef __attribute__((ext_vector_type(8))) short bf16x8;
typedef __attribute__((ext_vector_type(4))) float f32x4;

#define MF(a,b,c) __builtin_amdgcn_mfma_f32_16x16x32_bf16((a),(b),(c),0,0,0)

__device__ __forceinline__ unsigned short f2bf(float f) {
    union { float f; unsigned u; } v; v.f = f;
    return (unsigned short)((v.u + 0x7FFF + ((v.u >> 16) & 1)) >> 16);
}

// ---------------- fp32 -> bf16 conversion ----------------
__global__ __launch_bounds__(256) void cvt_kernel(const float* __restrict__ in,
                                                  unsigned short* __restrict__ out,
                                                  int n4) {
    int stride = gridDim.x * blockDim.x;
    for (int j = blockIdx.x * blockDim.x + threadIdx.x; j < n4; j += stride) {
        float4 v = reinterpret_cast<const float4*>(in)[j];
        ushort4 o;
        o.x = f2bf(v.x); o.y = f2bf(v.y); o.z = f2bf(v.z); o.w = f2bf(v.w);
        reinterpret_cast<ushort4*>(out)[j] = o;
    }
}

// dual-tensor fp32 -> bf16 conversion (one launch for w2 + u2)
__global__ __launch_bounds__(256) void cvt2_kernel(const float* __restrict__ in0,
                                                   unsigned short* __restrict__ out0,
                                                   const float* __restrict__ in1,
                                                   unsigned short* __restrict__ out1,
                                                   int n4) {
    const int half = gridDim.x >> 1;
    const bool lo = ((int)blockIdx.x < half);
    const float* in = lo ? in0 : in1;
    unsigned short* out = lo ? out0 : out1;
    const int bid = lo ? (int)blockIdx.x : (int)blockIdx.x - half;
    int stride = half * blockDim.x;
    for (int j = bid * blockDim.x + threadIdx.x; j < n4; j += stride) {
        float4 v = reinterpret_cast<const float4*>(in)[j];
        ushort4 o;
        o.x = f2bf(v.x); o.y = f2bf(v.y); o.z = f2bf(v.z); o.w = f2bf(v.w);
        reinterpret_cast<ushort4*>(out)[j] = o;
    }
}

// interleave gate/up weights for BOTH branches in one launch:
// W13[32g + j] = w1[16g + j]; W13[32g + 16 + j] = w3[16g + j]; same for U13 from u1/u3
__global__ __launch_bounds__(256) void cvt13x2_kernel(const float* __restrict__ w1,
                                                      const float* __restrict__ w3,
                                                      unsigned short* __restrict__ W13,
                                                      const float* __restrict__ u1,
                                                      const float* __restrict__ u3,
                                                      unsigned short* __restrict__ U13,
                                                      int n4) {
    const int half = gridDim.x >> 1;
    const bool lo = ((int)blockIdx.x < half);
    const float* a1 = lo ? w1 : u1;
    const float* a3 = lo ? w3 : u3;
    unsigned short* ob = lo ? W13 : U13;
    const int bid = lo ? (int)blockIdx.x : (int)blockIdx.x - half;
    int stride = half * blockDim.x;
    for (int j = bid * blockDim.x + threadIdx.x; j < n4; j += stride) {
        int flat = j << 2;
        int R = flat >> 11;          // row (DIM_H = 2048 cols)
        int col = flat & 2047;
        int orow = ((R >> 4) << 5) | (R & 15);
        float4 v1 = reinterpret_cast<const float4*>(a1)[j];
        float4 v3 = reinterpret_cast<const float4*>(a3)[j];
        ushort4 o1, o3;
        o1.x=f2bf(v1.x); o1.y=f2bf(v1.y); o1.z=f2bf(v1.z); o1.w=f2bf(v1.w);
        o3.x=f2bf(v3.x); o3.y=f2bf(v3.y); o3.z=f2bf(v3.z); o3.w=f2bf(v3.w);
        *reinterpret_cast<ushort4*>(&ob[(size_t)orow * DIM_H + col]) = o1;
        *reinterpret_cast<ushort4*>(&ob[(size_t)(orow + 16) * DIM_H + col]) = o3;
    }
}

// ---------------- mask compaction (256-row padding) ----------------
__global__ __launch_bounds__(256) void compact_kernel(const int* __restrict__ mask,
                                                      int* __restrict__ idx,
                                                      int* __restrict__ hdr) {
    __shared__ int cnt[256];
    const int t = threadIdx.x;
    const int base = t * 32;
    unsigned bits = 0;
#pragma unroll
    for (int j = 0; j < 32; ++j)
        if (mask[base + j] != 0) bits |= (1u << j);
    const int c = __popc(bits);
    cnt[t] = c;
    __syncthreads();
    for (int off = 1; off < 256; off <<= 1) {
        int v = cnt[t];
        int add = (t >= off) ? cnt[t - off] : 0;
        __syncthreads();
        cnt[t] = v + add;
        __syncthreads();
    }
    const int Mw  = cnt[255];
    const int MwP = (Mw + 255) & ~255;
    const int Mu  = TOKENS - Mw;
    const int MuP = (Mu + 255) & ~255;

    for (int j = t; j < CROWS; j += 256) idx[j] = -1;
    __syncthreads();

    int pw = cnt[t] - c;
    int pz = base - pw;
#pragma unroll
    for (int j = 0; j < 32; ++j) {
        int tok = base + j;
        if ((bits >> j) & 1) idx[pw++] = tok;
        else                 idx[MwP + pz++] = tok;
    }
    if (t == 0) {
        hdr[0] = MwP >> 8;           // w-blocks (256-row units)
        hdr[1] = (MwP + MuP) >> 8;   // total blocks
        hdr[2] = Mw;
        hdr[3] = Mu;
    }
}

// ================= shared GEMM machinery =================
// slice = R rows x 32 cols bf16 (64B rows); swizzle (16B units): phys c' = c16 ^ ((row>>1)&3)
// applied identically on pre-swizzled global src + ds_read addr (both-sides involution).

#define LDF4(D0,D1,D2,D3, SB, RB) do { \
    const unsigned short* _sl = &smem[(SB)]; \
    D0 = *reinterpret_cast<const bf16x8*>(&_sl[((RB) +  0)*32 + c16r]); \
    D1 = *reinterpret_cast<const bf16x8*>(&_sl[((RB) + 16)*32 + c16r]); \
    D2 = *reinterpret_cast<const bf16x8*>(&_sl[((RB) + 32)*32 + c16r]); \
    D3 = *reinterpret_cast<const bf16x8*>(&_sl[((RB) + 48)*32 + c16r]); \
} while(0)

#define LDF2(D0,D1, SB, RB) do { \
    const unsigned short* _sl = &smem[(SB)]; \
    D0 = *reinterpret_cast<const bf16x8*>(&_sl[((RB) +  0)*32 + c16r]); \
    D1 = *reinterpret_cast<const bf16x8*>(&_sl[((RB) + 16)*32 + c16r]); \
} while(0)

#define STAGE2(UB_, S0_, S1_, KOFS_) do { \
    __builtin_amdgcn_global_load_lds((const __attribute__((address_space(1))) void*)((S0_) + (KOFS_)), \
        (__attribute__((address_space(3))) void*)&smem[(UB_) + wave*512], 16, 0, 0); \
    __builtin_amdgcn_global_load_lds((const __attribute__((address_space(1))) void*)((S1_) + (KOFS_)), \
        (__attribute__((address_space(3))) void*)&smem[(UB_) + 4096 + wave*512], 16, 0, 0); \
} while(0)

#define STAGE1(UB_, S0_, KOFS_) \
    __builtin_amdgcn_global_load_lds((const __attribute__((address_space(1))) void*)((S0_) + (KOFS_)), \
        (__attribute__((address_space(3))) void*)&smem[(UB_) + wave*512], 16, 0, 0)

#define MFMA16Q(AF0,AF1,AF2,AF3, B0,B1,B2,B3) do { \
  acc[0][0]=MF(AF0,B0,acc[0][0]); acc[0][1]=MF(AF0,B1,acc[0][1]); acc[0][2]=MF(AF0,B2,acc[0][2]); acc[0][3]=MF(AF0,B3,acc[0][3]); \
  acc[1][0]=MF(AF1,B0,acc[1][0]); acc[1][1]=MF(AF1,B1,acc[1][1]); acc[1][2]=MF(AF1,B2,acc[1][2]); acc[1][3]=MF(AF1,B3,acc[1][3]); \
  acc[2][0]=MF(AF2,B0,acc[2][0]); acc[2][1]=MF(AF2,B1,acc[2][1]); acc[2][2]=MF(AF2,B2,acc[2][2]); acc[2][3]=MF(AF2,B3,acc[2][3]); \
  acc[3][0]=MF(AF3,B0,acc[3][0]); acc[3][1]=MF(AF3,B1,acc[3][1]); acc[3][2]=MF(AF3,B2,acc[3][2]); acc[3][3]=MF(AF3,B3,acc[3][3]); \
} while(0)

// ---------------- GEMM1: 128x256 / BK=64 / 8 waves (2Mx4N) / triple-buffer, 1 sync per K-tile ----
// Exact gemm2-main loop structure (proven) with gemm1's gather + dual-branch + silu-mul epilogue.
// LDS 144KB: 3 buf x { A[128x32]k0, A k1, B[256x32]k0, B k1 } = 24576 elems each.
// Grid 64 N-tiles x 68 rb = 4352 = 17 clean rounds; rb-fast: concurrent blocks per XCD share one
// 1MB W13-panel (L2-hot) while streaming gathered x tiles.
__global__ __launch_bounds__(512, 2) void gemm1_kernel(
    const unsigned short* __restrict__ xb,
    const unsigned short* __restrict__ W13,
    const unsigned short* __restrict__ U13,
    const int* __restrict__ idx, const int* __restrict__ hdr,
    unsigned short* __restrict__ P)
{
    __shared__ __align__(16) unsigned short smem[73728];  // 144 KB
    const int wB2  = hdr[0] * 2;               // 128-row units
    const int rbT2 = hdr[1] * 2;
    const int nwg = gridDim.x;                 // 4352
    const int q8  = nwg >> 3;                  // 544
    const int swz = ((int)blockIdx.x & 7) * q8 + ((int)blockIdx.x >> 3);
    const int rb = swz % 68;                   // M-block (128 compacted rows), fast axis
    const int bx = swz / 68;                   // N-tile (64 tiles of 256 W13-rows)
    if (rb >= rbT2) return;
    const unsigned short* Bm = (rb < wB2) ? W13 : U13;
    const int bm0 = rb << 7;                   // *128
    const int bn0 = bx << 8;                   // *256

    const int tid  = threadIdx.x;
    const int lane = tid & 63;
    const int wave = tid >> 6;
    const int wrM = wave >> 2;                 // 0..1
    const int wcN = wave & 3;                  // 0..3
    const int rAb = wrM * 64 + (lane & 15);
    const int rBb = wcN * 64 + (lane & 15);
    const int c16r = (((lane >> 4) ^ ((lane >> 1) & 3))) << 3;

    const int r0 = tid >> 2, r1 = 128 + r0;
    const int c0 = ((tid & 3) ^ ((r0 >> 1) & 3)) << 3;
    const int c1 = ((tid & 3) ^ ((r1 >> 1) & 3)) << 3;
    int t0 = idx[bm0 + r0]; if (t0 < 0) t0 = 0;
    const unsigned short* sa0 = xb + (size_t)t0 * DIM_H + c0;           // A rows 0..127 (gathered)
    const unsigned short* sb0 = Bm + (size_t)(bn0 + r0) * DIM_H + c0;
    const unsigned short* sb1 = Bm + (size_t)(bn0 + r1) * DIM_H + c1;

    f32x4 acc[4][4] = {};
    bf16x8 af0, af1, af2, af3, af4, af5, af6, af7;
    bf16x8 bfr0, bfr1, bfr2, bfr3, bfr4, bfr5, bfr6, bfr7;

    // prologue: t0 -> buf0, t1 -> buf1 (6 glls each)
    STAGE1(0,     sa0, 0);
    STAGE1(4096,  sa0, 32);
    STAGE2(8192,  sb0, sb1, 0);
    STAGE2(16384, sb0, sb1, 32);
    STAGE1(24576,         sa0, 64);
    STAGE1(24576 + 4096,  sa0, 96);
    STAGE2(24576 + 8192,  sb0, sb1, 64);
    STAGE2(24576 + 16384, sb0, sb1, 96);
    asm volatile("s_waitcnt vmcnt(6)" ::: "memory");   // t0 ready
    __builtin_amdgcn_s_barrier();
    int ko = 128, cb = 0;
    for (int t = 0; t < 32; ++t) {                     // K = 2048
        const int base = cb * 24576;
        int nb = base + 49152; if (nb >= 73728) nb -= 73728;   // (cb+2)%3
        // reads (16 b128)
        LDF4(af0,af1,af2,af3,     base,          rAb);
        LDF4(af4,af5,af6,af7,     base + 4096,   rAb);
        LDF4(bfr0,bfr1,bfr2,bfr3, base + 8192,   rBb);
        LDF4(bfr4,bfr5,bfr6,bfr7, base + 16384,  rBb);
        // stage t+2 -> nb (tail overrun <=208B stays inside ws, never consumed)
        STAGE1(nb,         sa0, ko);
        STAGE1(nb + 4096,  sa0, ko + 32);
        STAGE2(nb + 8192,  sb0, sb1, ko);
        STAGE2(nb + 16384, sb0, sb1, ko + 32);
        ko += 64;
        __builtin_amdgcn_s_setprio(1);
        MFMA16Q(af0,af1,af2,af3, bfr0,bfr1,bfr2,bfr3);   // k0
        MFMA16Q(af4,af5,af6,af7, bfr4,bfr5,bfr6,bfr7);   // k1
        __builtin_amdgcn_s_setprio(0);
        asm volatile("s_waitcnt vmcnt(6)" ::: "memory"); // t+1's loads landed
        __builtin_amdgcn_s_barrier();
        cb = (cb == 2) ? 0 : cb + 1;
    }

    // epilogue: n-frag pairs (2q, 2q+1) = (h1, h3) for the same 16 P-cols
    const int crow = (lane >> 4) << 2;
    const int ccol = lane & 15;
    unsigned short* Pw = P + (size_t)(bm0 + wrM * 64) * DIM_I
                           + (size_t)bx * 128 + wcN * 32 + ccol;
#pragma unroll
    for (int m = 0; m < 4; ++m) {
#pragma unroll
        for (int q = 0; q < 2; ++q) {
            f32x4 h1 = acc[m][2 * q];
            f32x4 h3 = acc[m][2 * q + 1];
#pragma unroll
            for (int r = 0; r < 4; ++r) {
                float a = h1[r];
                float p = a * (1.0f / (1.0f + __expf(-a))) * h3[r];
                Pw[(size_t)(m * 16 + crow + r) * DIM_I + q * 16] = f2bf(p);
            }
        }
    }
}

// ---------------- GEMM2 main: 128x256 / BK=64 / 8 waves / triple-buffer, rb < 64 only ----------
// grid exactly 512 = 8 bx x 64 rb -> 2 clean dispatch rounds, no tail (rbT2 >= 64 always).
__global__ __launch_bounds__(512, 2) void gemm2_kernel(
    const unsigned short* __restrict__ P,
    const unsigned short* __restrict__ w2b, const unsigned short* __restrict__ u2b,
    const int* __restrict__ idx, const int* __restrict__ hdr,
    float* __restrict__ out)
{
    __shared__ __align__(16) unsigned short smem[73728];  // 144 KB
    const int wB2  = hdr[0] * 2;               // 128-row units
    const int rbT2 = hdr[1] * 2;
    const int nwg = gridDim.x;                 // 512
    const int q8  = nwg >> 3;                  // 64
    const int swz = ((int)blockIdx.x & 7) * q8 + ((int)blockIdx.x >> 3);
    const int rb = swz & 63;                   // rb fast: each XCD pins one bx panel
    const int bx = swz >> 6;                   // 0..7
    if (rb >= rbT2) return;                    // never true (rbT2 >= 64); kept for safety
    const unsigned short* Bm = (rb < wB2) ? w2b : u2b;
    const int bm0 = rb << 7;                   // *128
    const int bn0 = bx << 8;                   // *256

    const int tid  = threadIdx.x;
    const int lane = tid & 63;
    const int wave = tid >> 6;
    const int wrM = wave >> 2;                 // 0..1
    const int wcN = wave & 3;                  // 0..3
    const int rAb = wrM * 64 + (lane & 15);
    const int rBb = wcN * 64 + (lane & 15);
    const int c16r = (((lane >> 4) ^ ((lane >> 1) & 3))) << 3;

    const int r0 = tid >> 2, r1 = 128 + r0;
    const int c0 = ((tid & 3) ^ ((r0 >> 1) & 3)) << 3;
    const int c1 = ((tid & 3) ^ ((r1 >> 1) & 3)) << 3;
    const unsigned short* sa0 = P  + (size_t)(bm0 + r0) * DIM_I + c0;   // A rows 0..127
    const unsigned short* sb0 = Bm + (size_t)(bn0 + r0) * DIM_I + c0;
    const unsigned short* sb1 = Bm + (size_t)(bn0 + r1) * DIM_I + c1;

    f32x4 acc[4][4] = {};
    bf16x8 af0, af1, af2, af3, af4, af5, af6, af7;
    bf16x8 bfr0, bfr1, bfr2, bfr3, bfr4, bfr5, bfr6, bfr7;

    // prologue: t0 -> buf0, t1 -> buf1
    STAGE1(0,     sa0, 0);
    STAGE1(4096,  sa0, 32);
    STAGE2(8192,  sb0, sb1, 0);
    STAGE2(16384, sb0, sb1, 32);
    STAGE1(24576,         sa0, 64);
    STAGE1(24576 + 4096,  sa0, 96);
    STAGE2(24576 + 8192,  sb0, sb1, 64);
    STAGE2(24576 + 16384, sb0, sb1, 96);
    asm volatile("s_waitcnt vmcnt(6)" ::: "memory");   // t0 ready
    __builtin_amdgcn_s_barrier();
    int ko = 128, cb = 0;
    for (int t = 0; t < 128; ++t) {
        const int base = cb * 24576;
        int nb = base + 49152; if (nb >= 73728) nb -= 73728;   // (cb+2)%3
        // reads (16 b128)
        LDF4(af0,af1,af2,af3,     base,          rAb);
        LDF4(af4,af5,af6,af7,     base + 4096,   rAb);
        LDF4(bfr0,bfr1,bfr2,bfr3, base + 8192,   rBb);
        LDF4(bfr4,bfr5,bfr6,bfr7, base + 16384,  rBb);
        // stage t+2 -> nb
        STAGE1(nb,         sa0, ko);
        STAGE1(nb + 4096,  sa0, ko + 32);
        STAGE2(nb + 8192,  sb0, sb1, ko);
        STAGE2(nb + 16384, sb0, sb1, ko + 32);
        ko += 64;
        __builtin_amdgcn_s_setprio(1);
        MFMA16Q(af0,af1,af2,af3, bfr0,bfr1,bfr2,bfr3);   // k0
        MFMA16Q(af4,af5,af6,af7, bfr4,bfr5,bfr6,bfr7);   // k1
        __builtin_amdgcn_s_setprio(0);
        asm volatile("s_waitcnt vmcnt(6)" ::: "memory"); // drains t+1's loads (2-phase cover)
        __builtin_amdgcn_s_barrier();
        cb = (cb == 2) ? 0 : cb + 1;
    }

    const int crow = (lane >> 4) << 2;
    const int ccol = lane & 15;
#pragma unroll
    for (int m = 0; m < 4; ++m) {
#pragma unroll
        for (int r = 0; r < 4; ++r) {
            int rowc = bm0 + wrM * 64 + m * 16 + crow + r;
            int g = idx[rowc];
            if (g >= 0) {
                float* op = out + (size_t)g * DIM_H + bn0 + wcN * 64 + ccol;
#pragma unroll
                for (int n = 0; n < 4; ++n) op[n * 16] = acc[m][n][r];
            }
        }
    }
}

// ---------------- GEMM2 tail: rows rb in [64, rbT2), 64x64 tiles, BK=64, grid 256 ----------
__global__ __launch_bounds__(256, 2) void gemm2_tail_kernel(
    const unsigned short* __restrict__ P,
    const unsigned short* __restrict__ w2b, const unsigned short* __restrict__ u2b,
    const int* __restrict__ idx, const int* __restrict__ hdr,
    float* __restrict__ out)
{
    __shared__ __align__(16) unsigned short smem[24576];  // 48 KB
    const int wB2  = hdr[0] * 2;
    const int rbT2 = hdr[1] * 2;
    const int b   = (int)blockIdx.x;           // [rbs:2][sub:1][bx:5] = 256 blocks
    const int bx  = b & 31;                    // 32 col tiles of 64
    const int sub = (b >> 5) & 1;              // 64-row half of the 128-row slab
    const int rb  = 64 + (b >> 6);             // 64..67
    if (rb >= rbT2) return;
    const unsigned short* Bm = (rb < wB2) ? w2b : u2b;
    const int bm0 = (rb << 7) + (sub << 6);
    const int bn0 = bx << 6;

    const int tid  = threadIdx.x;
    const int lane = tid & 63;
    const int wave = tid >> 6;                 // 0..3
    const int wrM = wave >> 1;                 // 0..1
    const int wcN = wave & 1;                  // 0..1
    const int rAb = wrM * 32 + (lane & 15);
    const int rBb = wcN * 32 + (lane & 15);
    const int c16r = (((lane >> 4) ^ ((lane >> 1) & 3))) << 3;

    const int r0 = tid >> 2;                   // 0..63
    const int c0 = ((tid & 3) ^ ((r0 >> 1) & 3)) << 3;
    const unsigned short* sa0 = P  + (size_t)(bm0 + r0) * DIM_I + c0;
    const unsigned short* sb0 = Bm + (size_t)(bn0 + r0) * DIM_I + c0;

    f32x4 acc[2][2] = {};
    bf16x8 a00, a01, a10, a11, b00, b01, b10, b11;

    // prologue: t0 -> buf0 (4 glls), t1 -> buf1 (4 glls)
    STAGE1(0,    sa0, 0);  STAGE1(2048,        sa0, 32);
    STAGE1(4096, sb0, 0);  STAGE1(6144,        sb0, 32);
    STAGE1(8192,  sa0, 64); STAGE1(8192 + 2048, sa0, 96);
    STAGE1(8192 + 4096, sb0, 64); STAGE1(8192 + 6144, sb0, 96);
    asm volatile("s_waitcnt vmcnt(4)" ::: "memory");       // t0 landed (mine)
    __builtin_amdgcn_s_barrier();                          // t0 landed (all)
    int ko = 128, cb = 0;
    for (int t = 0; t < 128; ++t) {
        const int base = cb * 8192;
        int nb = base + 16384; if (nb >= 24576) nb -= 24576;   // (cb+2)%3
        LDF2(a00,a01, base,        rAb);                   // k0 A
        LDF2(a10,a11, base + 2048, rAb);                   // k1 A
        LDF2(b00,b01, base + 4096, rBb);                   // k0 B
        LDF2(b10,b11, base + 6144, rBb);                   // k1 B
        STAGE1(nb,        sa0, ko); STAGE1(nb + 2048, sa0, ko + 32);  // stage t+2
        STAGE1(nb + 4096, sb0, ko); STAGE1(nb + 6144, sb0, ko + 32);
        ko += 64;
        __builtin_amdgcn_s_setprio(1);
        acc[0][0]=MF(a00,b00,acc[0][0]); acc[0][1]=MF(a00,b01,acc[0][1]);
        acc[1][0]=MF(a01,b00,acc[1][0]); acc[1][1]=MF(a01,b01,acc[1][1]);
        acc[0][0]=MF(a10,b10,acc[0][0]); acc[0][1]=MF(a10,b11,acc[0][1]);
        acc[1][0]=MF(a11,b10,acc[1][0]); acc[1][1]=MF(a11,b11,acc[1][1]);
        __builtin_amdgcn_s_setprio(0);
        asm volatile("s_waitcnt vmcnt(4)" ::: "memory");      // t+1 landed (mine)
        __builtin_amdgcn_s_barrier();                         // t+1 landed (all)
        cb = (cb == 2) ? 0 : cb + 1;
    }

    const int crow = (lane >> 4) << 2;
    const int ccol = lane & 15;
#pragma unroll
    for (int m = 0; m < 2; ++m) {
#pragma unroll
        for (int r = 0; r < 4; ++r) {
            int rowc = bm0 + wrM * 32 + m * 16 + crow + r;
            int g = idx[rowc];
            if (g >= 0) {
                float* op = out + (size_t)g * DIM_H + bn0 + wcN * 32 + ccol;
#pragma unroll
                for (int n = 0; n < 2; ++n) op[n * 16] = acc[m][n][r];
            }
        }
    }
}

extern "C" void kernel_launch(void* const* d_in, const int* in_sizes, int n_in,
                              void* d_out, int out_size, void* d_ws, size_t ws_size,
                              hipStream_t stream) {
    const float* x    = (const float*)d_in[0];
    const int*   mask = (const int*)d_in[1];
    const float* w1 = (const float*)d_in[2];
    const float* w2 = (const float*)d_in[3];
    const float* w3 = (const float*)d_in[4];
    const float* u1 = (const float*)d_in[5];
    const float* u2 = (const float*)d_in[6];
    const float* u3 = (const float*)d_in[7];
    float* out = (float*)d_out;

    const size_t XN   = (size_t)TOKENS * DIM_H;      // 16.78M
    const size_t WN   = (size_t)DIM_I * DIM_H;       // 16.78M
    const size_t PN   = (size_t)CROWS * DIM_I;       // 71.3M
    const size_t W13N = 2 * WN;                      // 33.55M

    unsigned short* ws  = (unsigned short*)d_ws;
    unsigned short* xb  = ws;                        // XN
    unsigned short* Pb  = xb + XN;                   // PN
    unsigned short* W13 = Pb + PN;                   // W13N
    unsigned short* U13 = W13 + W13N;                // W13N
    int* idx = (int*)(U13 + W13N);                   // CROWS ints
    int* hdr = idx + CROWS;                          // 8 ints
    // after gemm1, W13/U13 space is reused for the (smaller) down-proj weights
    unsigned short* w2b = W13;
    unsigned short* u2b = U13;

    const int cvtBlocks = 2048;
    const int n4 = (int)(WN / 4);

    cvt_kernel   <<<cvtBlocks, 256, 0, stream>>>(x, xb, (int)(XN / 4));
    cvt13x2_kernel<<<2 * cvtBlocks, 256, 0, stream>>>(w1, w3, W13, u1, u3, U13, n4);
    compact_kernel<<<1, 256, 0, stream>>>(mask, idx, hdr);

    gemm1_kernel<<<64 * 68, 512, 0, stream>>>(xb, W13, U13, idx, hdr, Pb);

    cvt2_kernel<<<2 * cvtBlocks, 256, 0, stream>>>(w2, w2b, u2, u2b, n4);

    gemm2_kernel<<<512, 512, 0, stream>>>(Pb, w2b, u2b, idx, hdr, out);
    gemm2_tail_kernel<<<256, 256, 0, stream>>>(Pb, w2b, u2b, idx, hdr, out);
}

// Round 19
// 977.329 us; speedup vs baseline: 1.1113x; 1.1113x over previous
//
#include <hip/hip_runtime.h>
#include <hip/hip_bf16.h>
#include <stdint.h>

#define DIM_H 2048
#define DIM_I 8192
#define TOKENS 8192
#define RB256 34            // max 256-row compacted blocks (32 + 2 pad)
#define CROWS (RB256*256)   // 8704

typedef __attribute__((ext_vector_type(8))) short bf16x8;
typedef __attribute__((ext_vector_type(4))) float f32x4;

#define MF(a,b,c) __builtin_amdgcn_mfma_f32_16x16x32_bf16((a),(b),(c),0,0,0)

__device__ __forceinline__ unsigned short f2bf(float f) {
    union { float f; unsigned u; } v; v.f = f;
    return (unsigned short)((v.u + 0x7FFF + ((v.u >> 16) & 1)) >> 16);
}

// ---------------- fp32 -> bf16 conversion ----------------
__global__ __launch_bounds__(256) void cvt_kernel(const float* __restrict__ in,
                                                  unsigned short* __restrict__ out,
                                                  int n4) {
    int stride = gridDim.x * blockDim.x;
    for (int j = blockIdx.x * blockDim.x + threadIdx.x; j < n4; j += stride) {
        float4 v = reinterpret_cast<const float4*>(in)[j];
        ushort4 o;
        o.x = f2bf(v.x); o.y = f2bf(v.y); o.z = f2bf(v.z); o.w = f2bf(v.w);
        reinterpret_cast<ushort4*>(out)[j] = o;
    }
}

// dual-tensor fp32 -> bf16 conversion (one launch for w2 + u2)
__global__ __launch_bounds__(256) void cvt2_kernel(const float* __restrict__ in0,
                                                   unsigned short* __restrict__ out0,
                                                   const float* __restrict__ in1,
                                                   unsigned short* __restrict__ out1,
                                                   int n4) {
    const int half = gridDim.x >> 1;
    const bool lo = ((int)blockIdx.x < half);
    const float* in = lo ? in0 : in1;
    unsigned short* out = lo ? out0 : out1;
    const int bid = lo ? (int)blockIdx.x : (int)blockIdx.x - half;
    int stride = half * blockDim.x;
    for (int j = bid * blockDim.x + threadIdx.x; j < n4; j += stride) {
        float4 v = reinterpret_cast<const float4*>(in)[j];
        ushort4 o;
        o.x = f2bf(v.x); o.y = f2bf(v.y); o.z = f2bf(v.z); o.w = f2bf(v.w);
        reinterpret_cast<ushort4*>(out)[j] = o;
    }
}

// interleave gate/up weights for BOTH branches in one launch:
// W13[32g + j] = w1[16g + j]; W13[32g + 16 + j] = w3[16g + j]; same for U13 from u1/u3
__global__ __launch_bounds__(256) void cvt13x2_kernel(const float* __restrict__ w1,
                                                      const float* __restrict__ w3,
                                                      unsigned short* __restrict__ W13,
                                                      const float* __restrict__ u1,
                                                      const float* __restrict__ u3,
                                                      unsigned short* __restrict__ U13,
                                                      int n4) {
    const int half = gridDim.x >> 1;
    const bool lo = ((int)blockIdx.x < half);
    const float* a1 = lo ? w1 : u1;
    const float* a3 = lo ? w3 : u3;
    unsigned short* ob = lo ? W13 : U13;
    const int bid = lo ? (int)blockIdx.x : (int)blockIdx.x - half;
    int stride = half * blockDim.x;
    for (int j = bid * blockDim.x + threadIdx.x; j < n4; j += stride) {
        int flat = j << 2;
        int R = flat >> 11;          // row (DIM_H = 2048 cols)
        int col = flat & 2047;
        int orow = ((R >> 4) << 5) | (R & 15);
        float4 v1 = reinterpret_cast<const float4*>(a1)[j];
        float4 v3 = reinterpret_cast<const float4*>(a3)[j];
        ushort4 o1, o3;
        o1.x=f2bf(v1.x); o1.y=f2bf(v1.y); o1.z=f2bf(v1.z); o1.w=f2bf(v1.w);
        o3.x=f2bf(v3.x); o3.y=f2bf(v3.y); o3.z=f2bf(v3.z); o3.w=f2bf(v3.w);
        *reinterpret_cast<ushort4*>(&ob[(size_t)orow * DIM_H + col]) = o1;
        *reinterpret_cast<ushort4*>(&ob[(size_t)(orow + 16) * DIM_H + col]) = o3;
    }
}

// ---------------- mask compaction (256-row padding) ----------------
__global__ __launch_bounds__(256) void compact_kernel(const int* __restrict__ mask,
                                                      int* __restrict__ idx,
                                                      int* __restrict__ hdr) {
    __shared__ int cnt[256];
    const int t = threadIdx.x;
    const int base = t * 32;
    unsigned bits = 0;
#pragma unroll
    for (int j = 0; j < 32; ++j)
        if (mask[base + j] != 0) bits |= (1u << j);
    const int c = __popc(bits);
    cnt[t] = c;
    __syncthreads();
    for (int off = 1; off < 256; off <<= 1) {
        int v = cnt[t];
        int add = (t >= off) ? cnt[t - off] : 0;
        __syncthreads();
        cnt[t] = v + add;
        __syncthreads();
    }
    const int Mw  = cnt[255];
    const int MwP = (Mw + 255) & ~255;
    const int Mu  = TOKENS - Mw;
    const int MuP = (Mu + 255) & ~255;

    for (int j = t; j < CROWS; j += 256) idx[j] = -1;
    __syncthreads();

    int pw = cnt[t] - c;
    int pz = base - pw;
#pragma unroll
    for (int j = 0; j < 32; ++j) {
        int tok = base + j;
        if ((bits >> j) & 1) idx[pw++] = tok;
        else                 idx[MwP + pz++] = tok;
    }
    if (t == 0) {
        hdr[0] = MwP >> 8;           // w-blocks (256-row units)
        hdr[1] = (MwP + MuP) >> 8;   // total blocks
        hdr[2] = Mw;
        hdr[3] = Mu;
    }
}

// ================= shared GEMM machinery =================
// slice = R rows x 32 cols bf16 (64B rows); swizzle (16B units): phys c' = c16 ^ ((row>>1)&3)
// applied identically on pre-swizzled global src + ds_read addr (both-sides involution).

#define LDF4(D0,D1,D2,D3, SB, RB) do { \
    const unsigned short* _sl = &smem[(SB)]; \
    D0 = *reinterpret_cast<const bf16x8*>(&_sl[((RB) +  0)*32 + c16r]); \
    D1 = *reinterpret_cast<const bf16x8*>(&_sl[((RB) + 16)*32 + c16r]); \
    D2 = *reinterpret_cast<const bf16x8*>(&_sl[((RB) + 32)*32 + c16r]); \
    D3 = *reinterpret_cast<const bf16x8*>(&_sl[((RB) + 48)*32 + c16r]); \
} while(0)

#define LDF2(D0,D1, SB, RB) do { \
    const unsigned short* _sl = &smem[(SB)]; \
    D0 = *reinterpret_cast<const bf16x8*>(&_sl[((RB) +  0)*32 + c16r]); \
    D1 = *reinterpret_cast<const bf16x8*>(&_sl[((RB) + 16)*32 + c16r]); \
} while(0)

#define STAGE2(UB_, S0_, S1_, KOFS_) do { \
    __builtin_amdgcn_global_load_lds((const __attribute__((address_space(1))) void*)((S0_) + (KOFS_)), \
        (__attribute__((address_space(3))) void*)&smem[(UB_) + wave*512], 16, 0, 0); \
    __builtin_amdgcn_global_load_lds((const __attribute__((address_space(1))) void*)((S1_) + (KOFS_)), \
        (__attribute__((address_space(3))) void*)&smem[(UB_) + 4096 + wave*512], 16, 0, 0); \
} while(0)

#define STAGE1(UB_, S0_, KOFS_) \
    __builtin_amdgcn_global_load_lds((const __attribute__((address_space(1))) void*)((S0_) + (KOFS_)), \
        (__attribute__((address_space(3))) void*)&smem[(UB_) + wave*512], 16, 0, 0)

// ---------------- GEMM1: 256x256 / BK=64 / 8 waves (2Mx4N) / 2 phases per K-tile ----------------
// LDS 128KB: 2 buf x { A_k0, A_k1, B_k0, B_k1 } slices of 256x32 (16KB = 8192 elems)
#define MFMA32_G1() do { \
  acc[0][0]=MF(af0,bfr0,acc[0][0]); acc[0][1]=MF(af0,bfr1,acc[0][1]); acc[0][2]=MF(af0,bfr2,acc[0][2]); acc[0][3]=MF(af0,bfr3,acc[0][3]); \
  acc[1][0]=MF(af1,bfr0,acc[1][0]); acc[1][1]=MF(af1,bfr1,acc[1][1]); acc[1][2]=MF(af1,bfr2,acc[1][2]); acc[1][3]=MF(af1,bfr3,acc[1][3]); \
  acc[2][0]=MF(af2,bfr0,acc[2][0]); acc[2][1]=MF(af2,bfr1,acc[2][1]); acc[2][2]=MF(af2,bfr2,acc[2][2]); acc[2][3]=MF(af2,bfr3,acc[2][3]); \
  acc[3][0]=MF(af3,bfr0,acc[3][0]); acc[3][1]=MF(af3,bfr1,acc[3][1]); acc[3][2]=MF(af3,bfr2,acc[3][2]); acc[3][3]=MF(af3,bfr3,acc[3][3]); \
  acc[4][0]=MF(af4,bfr0,acc[4][0]); acc[4][1]=MF(af4,bfr1,acc[4][1]); acc[4][2]=MF(af4,bfr2,acc[4][2]); acc[4][3]=MF(af4,bfr3,acc[4][3]); \
  acc[5][0]=MF(af5,bfr0,acc[5][0]); acc[5][1]=MF(af5,bfr1,acc[5][1]); acc[5][2]=MF(af5,bfr2,acc[5][2]); acc[5][3]=MF(af5,bfr3,acc[5][3]); \
  acc[6][0]=MF(af6,bfr0,acc[6][0]); acc[6][1]=MF(af6,bfr1,acc[6][1]); acc[6][2]=MF(af6,bfr2,acc[6][2]); acc[6][3]=MF(af6,bfr3,acc[6][3]); \
  acc[7][0]=MF(af7,bfr0,acc[7][0]); acc[7][1]=MF(af7,bfr1,acc[7][1]); acc[7][2]=MF(af7,bfr2,acc[7][2]); acc[7][3]=MF(af7,bfr3,acc[7][3]); \
} while(0)

__global__ __launch_bounds__(512, 2) void gemm1_kernel(
    const unsigned short* __restrict__ xb,
    const unsigned short* __restrict__ W13,
    const unsigned short* __restrict__ U13,
    const int* __restrict__ idx, const int* __restrict__ hdr,
    unsigned short* __restrict__ P)
{
    __shared__ __align__(16) unsigned short smem[65536];  // 128 KB
    const int wB  = hdr[0];
    const int rbT = hdr[1];
    const int nwg = gridDim.x;                 // 64*RB256
    const int q8  = nwg >> 3;
    const int swzb = ((int)blockIdx.x & 7) * q8 + ((int)blockIdx.x >> 3);
    const int rb = swzb % RB256;               // M-block (fast axis per XCD)
    const int bx = swzb / RB256;               // N-tile
    if (rb >= rbT) return;
    const unsigned short* Bm = (rb < wB) ? W13 : U13;
    const int bm0 = rb << 8;
    const int bn0 = bx << 8;

    const int tid  = threadIdx.x;
    const int lane = tid & 63;
    const int wave = tid >> 6;
    const int wrM = wave >> 2;
    const int wcN = wave & 3;
    const int rAb = wrM * 128 + (lane & 15);
    const int rBb = wcN * 64 + (lane & 15);
    const int c16r = (((lane >> 4) ^ ((lane >> 1) & 3))) << 3;

    const int p0 = tid, p1 = 512 + tid;
    const int r0 = p0 >> 2, r1 = p1 >> 2;
    const int c0 = ((p0 & 3) ^ ((r0 >> 1) & 3)) << 3;
    const int c1 = ((p1 & 3) ^ ((r1 >> 1) & 3)) << 3;
    int t0 = idx[bm0 + r0]; if (t0 < 0) t0 = 0;
    int t1 = idx[bm0 + r1]; if (t1 < 0) t1 = 0;
    const unsigned short* sa0 = xb + (size_t)t0 * DIM_H + c0;
    const unsigned short* sa1 = xb + (size_t)t1 * DIM_H + c1;
    const unsigned short* sb0 = Bm + (size_t)(bn0 + r0) * DIM_H + c0;
    const unsigned short* sb1 = Bm + (size_t)(bn0 + r1) * DIM_H + c1;

    f32x4 acc[8][4] = {};
    bf16x8 af0, af1, af2, af3, af4, af5, af6, af7, bfr0, bfr1, bfr2, bfr3;

    // prologue: t0 {Ak0,Bk0,Ak1,Bk1}, t1 {Ak0,Bk0}
    STAGE2(0,     sa0, sa1, 0);
    STAGE2(16384, sb0, sb1, 0);
    STAGE2(8192,  sa0, sa1, 32);
    STAGE2(24576, sb0, sb1, 32);
    STAGE2(32768, sa0, sa1, 64);
    STAGE2(49152, sb0, sb1, 64);
    asm volatile("s_waitcnt vmcnt(8)" ::: "memory");   // t0 k0 ready
    __builtin_amdgcn_s_barrier();
    int ko = 96;
    for (int t = 0; t < 32; ++t) {
        const int cur = (t & 1) << 15;
        const int nxt = cur ^ 32768;
        // P1: k0 reads + stage t+1 k1 -> nxt
        LDF4(af0,af1,af2,af3, cur,          rAb);
        LDF4(af4,af5,af6,af7, cur,          rAb + 64);
        LDF4(bfr0,bfr1,bfr2,bfr3, cur + 16384, rBb);
        STAGE2(nxt + 8192,  sa0, sa1, ko);
        STAGE2(nxt + 24576, sb0, sb1, ko);
        __builtin_amdgcn_s_setprio(1);
        MFMA32_G1();
        __builtin_amdgcn_s_setprio(0);
        asm volatile("s_waitcnt vmcnt(8)" ::: "memory");  // drains t0k1/tk1 FIFO slot
        __builtin_amdgcn_s_barrier();
        // P2: k1 reads + stage t+2 k0 -> cur
        LDF4(af0,af1,af2,af3, cur + 8192,   rAb);
        LDF4(af4,af5,af6,af7, cur + 8192,   rAb + 64);
        LDF4(bfr0,bfr1,bfr2,bfr3, cur + 24576, rBb);
        STAGE2(cur,         sa0, sa1, ko + 32);
        STAGE2(cur + 16384, sb0, sb1, ko + 32);
        ko += 64;
        __builtin_amdgcn_s_setprio(1);
        MFMA32_G1();
        __builtin_amdgcn_s_setprio(0);
        asm volatile("s_waitcnt vmcnt(8)" ::: "memory");
        __builtin_amdgcn_s_barrier();
    }

    // epilogue: n-frag pairs (2q, 2q+1) = (h1, h3) for the same 16 P-cols
    const int crow = (lane >> 4) << 2;
    const int ccol = lane & 15;
    unsigned short* Pw = P + (size_t)(bm0 + wrM * 128) * DIM_I
                           + (size_t)bx * 128 + wcN * 32 + ccol;
#pragma unroll
    for (int m = 0; m < 8; ++m) {
#pragma unroll
        for (int q = 0; q < 2; ++q) {
            f32x4 h1 = acc[m][2 * q];
            f32x4 h3 = acc[m][2 * q + 1];
#pragma unroll
            for (int r = 0; r < 4; ++r) {
                float a = h1[r];
                float p = a * (1.0f / (1.0f + __expf(-a))) * h3[r];
                Pw[(size_t)(m * 16 + crow + r) * DIM_I + q * 16] = f2bf(p);
            }
        }
    }
}

// ---------------- GEMM2 main: 128x256 / BK=64 / 8 waves / triple-buffer, rb < 64 only ----------
// grid exactly 512 = 8 bx x 64 rb -> 2 clean dispatch rounds, no tail (rbT2 >= 64 always).
#define MFMA16Q(AF0,AF1,AF2,AF3, B0,B1,B2,B3) do { \
  acc[0][0]=MF(AF0,B0,acc[0][0]); acc[0][1]=MF(AF0,B1,acc[0][1]); acc[0][2]=MF(AF0,B2,acc[0][2]); acc[0][3]=MF(AF0,B3,acc[0][3]); \
  acc[1][0]=MF(AF1,B0,acc[1][0]); acc[1][1]=MF(AF1,B1,acc[1][1]); acc[1][2]=MF(AF1,B2,acc[1][2]); acc[1][3]=MF(AF1,B3,acc[1][3]); \
  acc[2][0]=MF(AF2,B0,acc[2][0]); acc[2][1]=MF(AF2,B1,acc[2][1]); acc[2][2]=MF(AF2,B2,acc[2][2]); acc[2][3]=MF(AF2,B3,acc[2][3]); \
  acc[3][0]=MF(AF3,B0,acc[3][0]); acc[3][1]=MF(AF3,B1,acc[3][1]); acc[3][2]=MF(AF3,B2,acc[3][2]); acc[3][3]=MF(AF3,B3,acc[3][3]); \
} while(0)

__global__ __launch_bounds__(512, 2) void gemm2_kernel(
    const unsigned short* __restrict__ P,
    const unsigned short* __restrict__ w2b, const unsigned short* __restrict__ u2b,
    const int* __restrict__ idx, const int* __restrict__ hdr,
    float* __restrict__ out)
{
    __shared__ __align__(16) unsigned short smem[73728];  // 144 KB
    const int wB2  = hdr[0] * 2;               // 128-row units
    const int rbT2 = hdr[1] * 2;
    const int nwg = gridDim.x;                 // 512
    const int q8  = nwg >> 3;                  // 64
    const int swz = ((int)blockIdx.x & 7) * q8 + ((int)blockIdx.x >> 3);
    const int rb = swz & 63;                   // rb fast: each XCD pins one bx panel
    const int bx = swz >> 6;                   // 0..7
    if (rb >= rbT2) return;                    // never true (rbT2 >= 64); kept for safety
    const unsigned short* Bm = (rb < wB2) ? w2b : u2b;
    const int bm0 = rb << 7;                   // *128
    const int bn0 = bx << 8;                   // *256

    const int tid  = threadIdx.x;
    const int lane = tid & 63;
    const int wave = tid >> 6;
    const int wrM = wave >> 2;                 // 0..1
    const int wcN = wave & 3;                  // 0..3
    const int rAb = wrM * 64 + (lane & 15);
    const int rBb = wcN * 64 + (lane & 15);
    const int c16r = (((lane >> 4) ^ ((lane >> 1) & 3))) << 3;

    const int r0 = tid >> 2, r1 = 128 + r0;
    const int c0 = ((tid & 3) ^ ((r0 >> 1) & 3)) << 3;
    const int c1 = ((tid & 3) ^ ((r1 >> 1) & 3)) << 3;
    const unsigned short* sa0 = P  + (size_t)(bm0 + r0) * DIM_I + c0;   // A rows 0..127
    const unsigned short* sb0 = Bm + (size_t)(bn0 + r0) * DIM_I + c0;
    const unsigned short* sb1 = Bm + (size_t)(bn0 + r1) * DIM_I + c1;

    f32x4 acc[4][4] = {};
    bf16x8 af0, af1, af2, af3, af4, af5, af6, af7;
    bf16x8 bfr0, bfr1, bfr2, bfr3, bfr4, bfr5, bfr6, bfr7;

    // prologue: t0 -> buf0, t1 -> buf1
    STAGE1(0,     sa0, 0);
    STAGE1(4096,  sa0, 32);
    STAGE2(8192,  sb0, sb1, 0);
    STAGE2(16384, sb0, sb1, 32);
    STAGE1(24576,         sa0, 64);
    STAGE1(24576 + 4096,  sa0, 96);
    STAGE2(24576 + 8192,  sb0, sb1, 64);
    STAGE2(24576 + 16384, sb0, sb1, 96);
    asm volatile("s_waitcnt vmcnt(6)" ::: "memory");   // t0 ready
    __builtin_amdgcn_s_barrier();
    int ko = 128, cb = 0;
    for (int t = 0; t < 128; ++t) {
        const int base = cb * 24576;
        int nb = base + 49152; if (nb >= 73728) nb -= 73728;   // (cb+2)%3
        // reads (16 b128)
        LDF4(af0,af1,af2,af3,     base,          rAb);
        LDF4(af4,af5,af6,af7,     base + 4096,   rAb);
        LDF4(bfr0,bfr1,bfr2,bfr3, base + 8192,   rBb);
        LDF4(bfr4,bfr5,bfr6,bfr7, base + 16384,  rBb);
        // stage t+2 -> nb
        STAGE1(nb,         sa0, ko);
        STAGE1(nb + 4096,  sa0, ko + 32);
        STAGE2(nb + 8192,  sb0, sb1, ko);
        STAGE2(nb + 16384, sb0, sb1, ko + 32);
        ko += 64;
        __builtin_amdgcn_s_setprio(1);
        MFMA16Q(af0,af1,af2,af3, bfr0,bfr1,bfr2,bfr3);   // k0
        MFMA16Q(af4,af5,af6,af7, bfr4,bfr5,bfr6,bfr7);   // k1
        __builtin_amdgcn_s_setprio(0);
        asm volatile("s_waitcnt vmcnt(6)" ::: "memory"); // drains t+1's loads (2-phase cover)
        __builtin_amdgcn_s_barrier();
        cb = (cb == 2) ? 0 : cb + 1;
    }

    const int crow = (lane >> 4) << 2;
    const int ccol = lane & 15;
#pragma unroll
    for (int m = 0; m < 4; ++m) {
#pragma unroll
        for (int r = 0; r < 4; ++r) {
            int rowc = bm0 + wrM * 64 + m * 16 + crow + r;
            int g = idx[rowc];
            if (g >= 0) {
                float* op = out + (size_t)g * DIM_H + bn0 + wcN * 64 + ccol;
#pragma unroll
                for (int n = 0; n < 4; ++n) op[n * 16] = acc[m][n][r];
            }
        }
    }
}

// ---------------- GEMM2 tail: rows rb in [64, rbT2), 64x64 tiles, BK=64, grid 256 ----------
__global__ __launch_bounds__(256, 2) void gemm2_tail_kernel(
    const unsigned short* __restrict__ P,
    const unsigned short* __restrict__ w2b, const unsigned short* __restrict__ u2b,
    const int* __restrict__ idx, const int* __restrict__ hdr,
    float* __restrict__ out)
{
    __shared__ __align__(16) unsigned short smem[24576];  // 48 KB
    const int wB2  = hdr[0] * 2;
    const int rbT2 = hdr[1] * 2;
    const int b   = (int)blockIdx.x;           // [rbs:2][sub:1][bx:5] = 256 blocks
    const int bx  = b & 31;                    // 32 col tiles of 64
    const int sub = (b >> 5) & 1;              // 64-row half of the 128-row slab
    const int rb  = 64 + (b >> 6);             // 64..67
    if (rb >= rbT2) return;
    const unsigned short* Bm = (rb < wB2) ? w2b : u2b;
    const int bm0 = (rb << 7) + (sub << 6);
    const int bn0 = bx << 6;

    const int tid  = threadIdx.x;
    const int lane = tid & 63;
    const int wave = tid >> 6;                 // 0..3
    const int wrM = wave >> 1;                 // 0..1
    const int wcN = wave & 1;                  // 0..1
    const int rAb = wrM * 32 + (lane & 15);
    const int rBb = wcN * 32 + (lane & 15);
    const int c16r = (((lane >> 4) ^ ((lane >> 1) & 3))) << 3;

    const int r0 = tid >> 2;                   // 0..63
    const int c0 = ((tid & 3) ^ ((r0 >> 1) & 3)) << 3;
    const unsigned short* sa0 = P  + (size_t)(bm0 + r0) * DIM_I + c0;
    const unsigned short* sb0 = Bm + (size_t)(bn0 + r0) * DIM_I + c0;

    f32x4 acc[2][2] = {};
    bf16x8 a00, a01, a10, a11, b00, b01, b10, b11;

    // prologue: t0 -> buf0 (4 glls), t1 -> buf1 (4 glls)
    STAGE1(0,    sa0, 0);  STAGE1(2048,        sa0, 32);
    STAGE1(4096, sb0, 0);  STAGE1(6144,        sb0, 32);
    STAGE1(8192,  sa0, 64); STAGE1(8192 + 2048, sa0, 96);
    STAGE1(8192 + 4096, sb0, 64); STAGE1(8192 + 6144, sb0, 96);
    asm volatile("s_waitcnt vmcnt(4)" ::: "memory");       // t0 landed (mine)
    __builtin_amdgcn_s_barrier();                          // t0 landed (all)
    int ko = 128, cb = 0;
    for (int t = 0; t < 128; ++t) {
        const int base = cb * 8192;
        int nb = base + 16384; if (nb >= 24576) nb -= 24576;   // (cb+2)%3
        LDF2(a00,a01, base,        rAb);                   // k0 A
        LDF2(a10,a11, base + 2048, rAb);                   // k1 A
        LDF2(b00,b01, base + 4096, rBb);                   // k0 B
        LDF2(b10,b11, base + 6144, rBb);                   // k1 B
        STAGE1(nb,        sa0, ko); STAGE1(nb + 2048, sa0, ko + 32);  // stage t+2
        STAGE1(nb + 4096, sb0, ko); STAGE1(nb + 6144, sb0, ko + 32);
        ko += 64;
        __builtin_amdgcn_s_setprio(1);
        acc[0][0]=MF(a00,b00,acc[0][0]); acc[0][1]=MF(a00,b01,acc[0][1]);
        acc[1][0]=MF(a01,b00,acc[1][0]); acc[1][1]=MF(a01,b01,acc[1][1]);
        acc[0][0]=MF(a10,b10,acc[0][0]); acc[0][1]=MF(a10,b11,acc[0][1]);
        acc[1][0]=MF(a11,b10,acc[1][0]); acc[1][1]=MF(a11,b11,acc[1][1]);
        __builtin_amdgcn_s_setprio(0);
        asm volatile("s_waitcnt vmcnt(4)" ::: "memory");      // t+1 landed (mine)
        __builtin_amdgcn_s_barrier();                         // t+1 landed (all)
        cb = (cb == 2) ? 0 : cb + 1;
    }

    const int crow = (lane >> 4) << 2;
    const int ccol = lane & 15;
#pragma unroll
    for (int m = 0; m < 2; ++m) {
#pragma unroll
        for (int r = 0; r < 4; ++r) {
            int rowc = bm0 + wrM * 32 + m * 16 + crow + r;
            int g = idx[rowc];
            if (g >= 0) {
                float* op = out + (size_t)g * DIM_H + bn0 + wcN * 32 + ccol;
#pragma unroll
                for (int n = 0; n < 2; ++n) op[n * 16] = acc[m][n][r];
            }
        }
    }
}

extern "C" void kernel_launch(void* const* d_in, const int* in_sizes, int n_in,
                              void* d_out, int out_size, void* d_ws, size_t ws_size,
                              hipStream_t stream) {
    const float* x    = (const float*)d_in[0];
    const int*   mask = (const int*)d_in[1];
    const float* w1 = (const float*)d_in[2];
    const float* w2 = (const float*)d_in[3];
    const float* w3 = (const float*)d_in[4];
    const float* u1 = (const float*)d_in[5];
    const float* u2 = (const float*)d_in[6];
    const float* u3 = (const float*)d_in[7];
    float* out = (float*)d_out;

    const size_t XN   = (size_t)TOKENS * DIM_H;      // 16.78M
    const size_t WN   = (size_t)DIM_I * DIM_H;       // 16.78M
    const size_t PN   = (size_t)CROWS * DIM_I;       // 71.3M
    const size_t W13N = 2 * WN;                      // 33.55M

    unsigned short* ws  = (unsigned short*)d_ws;
    unsigned short* xb  = ws;                        // XN
    unsigned short* Pb  = xb + XN;                   // PN
    unsigned short* W13 = Pb + PN;                   // W13N
    unsigned short* U13 = W13 + W13N;                // W13N
    int* idx = (int*)(U13 + W13N);                   // CROWS ints
    int* hdr = idx + CROWS;                          // 8 ints
    // after gemm1, W13/U13 space is reused for the (smaller) down-proj weights
    unsigned short* w2b = W13;
    unsigned short* u2b = U13;

    const int cvtBlocks = 2048;
    const int n4 = (int)(WN / 4);

    cvt_kernel   <<<cvtBlocks, 256, 0, stream>>>(x, xb, (int)(XN / 4));
    cvt13x2_kernel<<<2 * cvtBlocks, 256, 0, stream>>>(w1, w3, W13, u1, u3, U13, n4);
    compact_kernel<<<1, 256, 0, stream>>>(mask, idx, hdr);

    gemm1_kernel<<<64 * RB256, 512, 0, stream>>>(xb, W13, U13, idx, hdr, Pb);

    cvt2_kernel<<<2 * cvtBlocks, 256, 0, stream>>>(w2, w2b, u2, u2b, n4);

    gemm2_kernel<<<512, 512, 0, stream>>>(Pb, w2b, u2b, idx, hdr, out);
    gemm2_tail_kernel<<<256, 256, 0, stream>>>(Pb, w2b, u2b, idx, hdr, out);
}